// Round 4
// baseline (1877.045 us; speedup 1.0000x reference)
//
#include <hip/hip_runtime.h>
#include <hip/hip_bf16.h>
#include <cstdint>

// Shapes (compile-time constants for this problem)
#define B_    2
#define T_    1024
#define NT_   30
#define H_    1024
#define L_    8
#define F_    2816
#define NH_   16
#define R_    16
#define HD_   64
#define M_    2048          // B*T
#define NTP1_ 31

typedef unsigned short u16;
typedef short  s16x8 __attribute__((ext_vector_type(8)));   // MFMA bf16 operand
typedef unsigned short u16x4 __attribute__((ext_vector_type(4)));
typedef unsigned short u16x8 __attribute__((ext_vector_type(8)));
typedef float  f32x4 __attribute__((ext_vector_type(4)));

__device__ __forceinline__ u16 f2bf(float f){
  __hip_bfloat16 h = __float2bfloat16(f);
  return __builtin_bit_cast(unsigned short, h);
}
__device__ __forceinline__ float bf2f(u16 u){
  uint32_t v = (uint32_t)u << 16;
  return __builtin_bit_cast(float, v);
}

__device__ __forceinline__ void async16(const void* g, void* l){
  __builtin_amdgcn_global_load_lds((const __attribute__((address_space(1))) void*)g,
                                   (__attribute__((address_space(3))) void*)l, 16, 0, 0);
}

// ---------------------------------------------------------------------------
// Fold LoRA into weights, convert to bf16, TRANSPOSE to Wt[n][k].
// Wt[n][k] = W[k][n] + 2 * sum_r A[r][k] * Bm[n][r]
// ---------------------------------------------------------------------------
__global__ __launch_bounds__(256, 3) void fold_kernel(
    const float* __restrict__ W, const float* __restrict__ A,
    const float* __restrict__ Bm, u16* __restrict__ Wt,
    int K, int N, long strW, long strA, long strB, long strWt)
{
  const int mat = blockIdx.z;
  W  += (long)mat * strW;  A  += (long)mat * strA;
  Bm += (long)mat * strB;  Wt += (long)mat * strWt;
  const int k0 = blockIdx.x * 64, n0 = blockIdx.y * 64;
  __shared__ float Wt_s[64][65];   // [n][k]
  __shared__ float As[16][64];     // [r][k]
  __shared__ float Bs[64][20];     // [n][r]
  const int tid = threadIdx.x;
  {
    const int kr = tid >> 4;
    const int n4 = (tid & 15) * 4;
    #pragma unroll
    for (int p = 0; p < 4; p++){
      int krow = p * 16 + kr;
      float4 w = *(const float4*)(W + (long)(k0 + krow) * N + n0 + n4);
      Wt_s[n4+0][krow] = w.x; Wt_s[n4+1][krow] = w.y;
      Wt_s[n4+2][krow] = w.z; Wt_s[n4+3][krow] = w.w;
    }
    const int r = tid >> 4, kc = (tid & 15) * 4;
    *(float4*)&As[r][kc] = *(const float4*)(A + (long)r * K + k0 + kc);
    const int nb = tid >> 2, r4 = (tid & 3) * 4;
    float4 b = *(const float4*)(Bm + (long)(n0 + nb) * 16 + r4);
    Bs[nb][r4+0]=b.x; Bs[nb][r4+1]=b.y; Bs[nb][r4+2]=b.z; Bs[nb][r4+3]=b.w;
  }
  __syncthreads();
  const int ko = (tid & 7) * 8;
  const int na = tid >> 3;
  float bq0[16], bq1[16];
  #pragma unroll
  for (int c = 0; c < 4; c++){
    *(float4*)&bq0[c*4] = *(const float4*)&Bs[na][c*4];
    *(float4*)&bq1[c*4] = *(const float4*)&Bs[na+32][c*4];
  }
  float l0[8] = {}, l1[8] = {};
  #pragma unroll
  for (int r = 0; r < 16; r++){
    float a[8];
    *(float4*)&a[0] = *(const float4*)&As[r][ko];
    *(float4*)&a[4] = *(const float4*)&As[r][ko+4];
    #pragma unroll
    for (int j = 0; j < 8; j++){
      l0[j] += a[j] * bq0[r];
      l1[j] += a[j] * bq1[r];
    }
  }
  u16x8 o0, o1;
  #pragma unroll
  for (int j = 0; j < 8; j++){
    o0[j] = f2bf(Wt_s[na][ko+j]    + 2.0f * l0[j]);
    o1[j] = f2bf(Wt_s[na+32][ko+j] + 2.0f * l1[j]);
  }
  *(u16x8*)(Wt + (long)(n0+na)*K    + k0 + ko) = o0;
  *(u16x8*)(Wt + (long)(n0+na+32)*K + k0 + ko) = o1;
}

// ---------------------------------------------------------------------------
// h = x @ state_W + state_b.  grid M_, 256 thr.
// ---------------------------------------------------------------------------
__global__ __launch_bounds__(256) void embed_kernel(
    const float* __restrict__ x, const float* __restrict__ sw,
    const float* __restrict__ sb, float* __restrict__ h)
{
  const int m = blockIdx.x;
  const float* xr = x + (long)m * NT_;
  for (int jj = threadIdx.x; jj < H_; jj += 256){
    float acc = sb[jj];
    #pragma unroll
    for (int i = 0; i < NT_; i++) acc += xr[i] * sw[i * H_ + jj];
    h[(long)m * H_ + jj] = acc;
  }
}

// ---------------------------------------------------------------------------
// RMSNorm row -> bf16, optionally fusing h += sum_{z<4} p[z] (split-K partials),
// writing h back. grid M_, 256 thr.
// ---------------------------------------------------------------------------
__global__ __launch_bounds__(256) void rms_kernel(
    float* __restrict__ hsrc, const float* __restrict__ p,
    const float* __restrict__ w, u16* __restrict__ outp, int fuse)
{
  const int m = blockIdx.x, t = threadIdx.x;
  float4 v = ((const float4*)(hsrc + (long)m * H_))[t];
  if (fuse){
    #pragma unroll
    for (int z = 0; z < 4; z++){
      const float4 a = ((const float4*)(p + (long)z * M_ * H_ + (long)m * H_))[t];
      v.x += a.x; v.y += a.y; v.z += a.z; v.w += a.w;
    }
    ((float4*)(hsrc + (long)m * H_))[t] = v;
  }
  float ss = v.x*v.x + v.y*v.y + v.z*v.z + v.w*v.w;
  #pragma unroll
  for (int off = 32; off >= 1; off >>= 1) ss += __shfl_xor(ss, off);
  __shared__ float red[4];
  if ((t & 63) == 0) red[t >> 6] = ss;
  __syncthreads();
  const float scale = rsqrtf((red[0]+red[1]+red[2]+red[3]) * (1.0f/H_) + 1e-6f);
  const float4 wv = ((const float4*)w)[t];
  u16x4 o;
  o[0] = f2bf(v.x*scale*wv.x); o[1] = f2bf(v.y*scale*wv.y);
  o[2] = f2bf(v.z*scale*wv.z); o[3] = f2bf(v.w*scale*wv.w);
  *(u16x4*)(outp + (long)m * H_ + t * 4) = o;
}

// ---------------------------------------------------------------------------
// GEMM: C = A(M,K)bf16 @ Bt(N,K)bf16^T.  OUTBF=1 -> bf16 out, 0 -> fp32.
// Software-pipelined: BK=32, double-buffered LDS, ONE barrier per K-step;
// next tile's global_load_lds issued before compute so the vmcnt(0) drain
// at the barrier overlaps the MFMA phase.
// Swizzle: 64B rows span only 16 banks, so chunk col = p ^ ((row>>1)&3)
// (parity supplies the other 16 banks) -> 2-way max on ds_read_b128.
// grid (M/128, N/128, Z), 256 thr.
// ---------------------------------------------------------------------------
template<int OUTBF>
__global__ __launch_bounds__(256, 3) void gemm_bt(
    const u16* __restrict__ Ag, const u16* __restrict__ Btg, void* __restrict__ Cptr,
    int Ndim, int Klen, int Kstride, long zsA, long zsB, long zsC)
{
  Ag  += (long)blockIdx.z * zsA;
  Btg += (long)blockIdx.z * zsB;
  const int m0 = blockIdx.x * 128, n0 = blockIdx.y * 128;
  __shared__ alignas(16) u16 As[2][128 * 32];
  __shared__ alignas(16) u16 Bs[2][128 * 32];
  const int tid = threadIdx.x;
  const int wave = tid >> 6, lane = tid & 63;
  const int wm = (wave & 1) * 64, wn = (wave >> 1) * 64;
  const int fr = lane & 15, quad = lane >> 4;

  // staging indices: 128x32 u16 = 512 chunks of 16B; 2 chunks/thread/array
  const int r0 = tid >> 2, p0c = tid & 3;
  const int r1 = (256 + tid) >> 2, p1c = tid & 3;  // r1 = r0 + 64
  const int gc0 = (p0c ^ ((r0 >> 1) & 3)) * 8;
  const int gc1 = (p1c ^ ((r1 >> 1) & 3)) * 8;

  f32x4 acc[4][4] = {};
  const int nk = Klen >> 5;

  // prologue: stage tile 0 into buf 0
  async16(Ag  + (long)(m0 + r0) * Kstride + gc0, &As[0][tid * 8]);
  async16(Ag  + (long)(m0 + r1) * Kstride + gc1, &As[0][(256 + tid) * 8]);
  async16(Btg + (long)(n0 + r0) * Kstride + gc0, &Bs[0][tid * 8]);
  async16(Btg + (long)(n0 + r1) * Kstride + gc1, &Bs[0][(256 + tid) * 8]);
  __syncthreads();

  for (int k = 0; k < nk; k++){
    const int cur = k & 1, nxt = cur ^ 1;
    if (k + 1 < nk){
      const int kt = (k + 1) << 5;
      async16(Ag  + (long)(m0 + r0) * Kstride + kt + gc0, &As[nxt][tid * 8]);
      async16(Ag  + (long)(m0 + r1) * Kstride + kt + gc1, &As[nxt][(256 + tid) * 8]);
      async16(Btg + (long)(n0 + r0) * Kstride + kt + gc0, &Bs[nxt][tid * 8]);
      async16(Btg + (long)(n0 + r1) * Kstride + kt + gc1, &Bs[nxt][(256 + tid) * 8]);
    }
    s16x8 af[4], bg[4];
    #pragma unroll
    for (int i = 0; i < 4; i++){
      int rA = wm + i * 16 + fr;
      af[i] = *(const s16x8*)(&As[cur][rA * 32 + ((quad ^ ((rA >> 1) & 3)) * 8)]);
      int rB = wn + i * 16 + fr;
      bg[i] = *(const s16x8*)(&Bs[cur][rB * 32 + ((quad ^ ((rB >> 1) & 3)) * 8)]);
    }
    #pragma unroll
    for (int i = 0; i < 4; i++)
      #pragma unroll
      for (int j = 0; j < 4; j++)
        acc[i][j] = __builtin_amdgcn_mfma_f32_16x16x32_bf16(af[i], bg[j], acc[i][j], 0, 0, 0);
    __syncthreads();   // drains nxt loads (in flight during MFMA) + guards buf reuse
  }

  #pragma unroll
  for (int i = 0; i < 4; i++){
    int row0 = m0 + wm + i * 16 + quad * 4;
    #pragma unroll
    for (int j = 0; j < 4; j++){
      int col = n0 + wn + j * 16 + fr;
      #pragma unroll
      for (int r = 0; r < 4; r++){
        long idx = (long)(row0 + r) * Ndim + col;
        if (OUTBF){
          u16* C = (u16*)Cptr + (long)blockIdx.z * zsC;
          C[idx] = f2bf(acc[i][j][r]);
        } else {
          float* C = (float*)Cptr + (long)blockIdx.z * zsC;
          C[idx] = acc[i][j][r];
        }
      }
    }
  }
}

// ---------------------------------------------------------------------------
// Fused gate/up GEMM + SiLU, same pipelined structure (3 arrays, 48 KB LDS).
// act[m][n] = silu(A@Wg^T) * (A@Wu^T), bf16 out. grid (M/128, F/128), 256 thr.
// ---------------------------------------------------------------------------
__global__ __launch_bounds__(256, 2) void gemm_gu(
    const u16* __restrict__ Ag, const u16* __restrict__ Bgw,
    const u16* __restrict__ Buw, u16* __restrict__ actb)
{
  const int m0 = blockIdx.x * 128, n0 = blockIdx.y * 128;
  __shared__ alignas(16) u16 As[2][128 * 32];
  __shared__ alignas(16) u16 Bg_[2][128 * 32];
  __shared__ alignas(16) u16 Bu_[2][128 * 32];
  const int tid = threadIdx.x;
  const int wave = tid >> 6, lane = tid & 63;
  const int wm = (wave & 1) * 64, wn = (wave >> 1) * 64;
  const int fr = lane & 15, quad = lane >> 4;

  const int r0 = tid >> 2, p0c = tid & 3;
  const int r1 = (256 + tid) >> 2, p1c = tid & 3;
  const int gc0 = (p0c ^ ((r0 >> 1) & 3)) * 8;
  const int gc1 = (p1c ^ ((r1 >> 1) & 3)) * 8;

  f32x4 accg[4][4] = {}, accu[4][4] = {};
  const int nk = H_ >> 5;

  async16(Ag  + (long)(m0 + r0) * H_ + gc0, &As[0][tid * 8]);
  async16(Ag  + (long)(m0 + r1) * H_ + gc1, &As[0][(256 + tid) * 8]);
  async16(Bgw + (long)(n0 + r0) * H_ + gc0, &Bg_[0][tid * 8]);
  async16(Bgw + (long)(n0 + r1) * H_ + gc1, &Bg_[0][(256 + tid) * 8]);
  async16(Buw + (long)(n0 + r0) * H_ + gc0, &Bu_[0][tid * 8]);
  async16(Buw + (long)(n0 + r1) * H_ + gc1, &Bu_[0][(256 + tid) * 8]);
  __syncthreads();

  for (int k = 0; k < nk; k++){
    const int cur = k & 1, nxt = cur ^ 1;
    if (k + 1 < nk){
      const int kt = (k + 1) << 5;
      async16(Ag  + (long)(m0 + r0) * H_ + kt + gc0, &As[nxt][tid * 8]);
      async16(Ag  + (long)(m0 + r1) * H_ + kt + gc1, &As[nxt][(256 + tid) * 8]);
      async16(Bgw + (long)(n0 + r0) * H_ + kt + gc0, &Bg_[nxt][tid * 8]);
      async16(Bgw + (long)(n0 + r1) * H_ + kt + gc1, &Bg_[nxt][(256 + tid) * 8]);
      async16(Buw + (long)(n0 + r0) * H_ + kt + gc0, &Bu_[nxt][tid * 8]);
      async16(Buw + (long)(n0 + r1) * H_ + kt + gc1, &Bu_[nxt][(256 + tid) * 8]);
    }
    s16x8 af[4], bb[4];
    #pragma unroll
    for (int i = 0; i < 4; i++){
      int rA = wm + i * 16 + fr;
      af[i] = *(const s16x8*)(&As[cur][rA * 32 + ((quad ^ ((rA >> 1) & 3)) * 8)]);
    }
    #pragma unroll
    for (int i = 0; i < 4; i++){
      int rB = wn + i * 16 + fr;
      bb[i] = *(const s16x8*)(&Bg_[cur][rB * 32 + ((quad ^ ((rB >> 1) & 3)) * 8)]);
    }
    #pragma unroll
    for (int i = 0; i < 4; i++)
      #pragma unroll
      for (int j = 0; j < 4; j++)
        accg[i][j] = __builtin_amdgcn_mfma_f32_16x16x32_bf16(af[i], bb[j], accg[i][j], 0, 0, 0);
    #pragma unroll
    for (int i = 0; i < 4; i++){
      int rB = wn + i * 16 + fr;
      bb[i] = *(const s16x8*)(&Bu_[cur][rB * 32 + ((quad ^ ((rB >> 1) & 3)) * 8)]);
    }
    #pragma unroll
    for (int i = 0; i < 4; i++)
      #pragma unroll
      for (int j = 0; j < 4; j++)
        accu[i][j] = __builtin_amdgcn_mfma_f32_16x16x32_bf16(af[i], bb[j], accu[i][j], 0, 0, 0);
    __syncthreads();
  }

  #pragma unroll
  for (int i = 0; i < 4; i++){
    int row0 = m0 + wm + i * 16 + quad * 4;
    #pragma unroll
    for (int j = 0; j < 4; j++){
      int col = n0 + wn + j * 16 + fr;
      #pragma unroll
      for (int r = 0; r < 4; r++){
        float g = accg[i][j][r], u = accu[i][j][r];
        float act = g / (1.0f + __expf(-g)) * u;
        actb[(long)(row0 + r) * F_ + col] = f2bf(act);
      }
    }
  }
}

// ---------------------------------------------------------------------------
// Merged RoPE + V-transpose. Blocks [0, M_): rope for one (b,t).
// Blocks [M_, M_+1024): vtrans (bh, tchunk).
// ---------------------------------------------------------------------------
__global__ __launch_bounds__(256) void rope_vt_kernel(
    const u16* __restrict__ qkv, u16* __restrict__ qr, u16* __restrict__ kr,
    u16* __restrict__ vt)
{
  const int bid = blockIdx.x;
  if (bid < M_){
    const int m = bid;
    const int b = m >> 10, t = m & 1023;
    for (int w = threadIdx.x; w < 1024; w += 256){
      const int sel = w >> 9;          // 0=q 1=k
      const int hh  = (w >> 5) & 15;
      const int i   = w & 31;
      const u16* src = qkv + (long)sel * M_ * H_ + (long)m * H_ + hh * HD_;
      float x1 = bf2f(src[i]), x2 = bf2f(src[i + 32]);
      float freq = exp2f((float)i * (-13.287712379549449f / 32.0f)); // 10000^(-i/32)
      float ang = (float)t * freq;
      float sn, cs; __sincosf(ang, &sn, &cs);
      u16* dst = (sel ? kr : qr) + ((long)((b * NH_ + hh) * T_ + t)) * HD_;
      dst[i]      = f2bf(x1 * cs - x2 * sn);
      dst[i + 32] = f2bf(x2 * cs + x1 * sn);
    }
  } else {
    const int v = bid - M_;            // 0..1023
    const int bh = v >> 5, tch = v & 31;
    const int b = bh >> 4, hh = bh & 15;
    const int d = threadIdx.x & 63, tc = threadIdx.x >> 6;
    const int t0 = tch * 32 + tc * 8;
    const u16* src = qkv + (long)2 * M_ * H_ + (long)b * T_ * H_ + hh * HD_ + d;
    u16x8 o;
    #pragma unroll
    for (int j = 0; j < 8; j++) o[j] = src[(long)(t0 + j) * H_];
    *(u16x8*)(vt + ((long)bh * HD_ + d) * T_ + t0) = o;
  }
}

// ---------------------------------------------------------------------------
// Flash attention. grid (T_/64, B_*NH_), 256 thr. 64-q x 128-k tiles.
// ---------------------------------------------------------------------------
__global__ __launch_bounds__(256, 2) void attn_kernel(
    const u16* __restrict__ qr, const u16* __restrict__ kr,
    const u16* __restrict__ vt, u16* __restrict__ att)
{
  const int qt = blockIdx.x;
  const int bh = blockIdx.y;
  const int b = bh >> 4, hh = bh & 15;
  __shared__ alignas(16) u16 Qs[64 * 64];
  __shared__ alignas(16) u16 Ks[128 * 64];
  __shared__ alignas(16) u16 Vs[64 * 128];
  __shared__ alignas(16) u16 Ps[64 * 136];
  const int tid = threadIdx.x;
  const int wave = tid >> 6, lane = tid & 63, fr = lane & 15, quad = lane >> 4;
  const int wrow = wave * 16;

  const u16* qg = qr + ((long)bh * T_ + qt * 64) * HD_;
  #pragma unroll
  for (int c = 0; c < 2; c++){
    int lin = c * 256 + tid, row = lin >> 3, p = lin & 7;
    async16(qg + row * HD_ + ((p ^ (row & 7)) * 8), Qs + lin * 8);
  }
  f32x4 o_acc[4] = {};
  float m_r[4] = {-1e30f, -1e30f, -1e30f, -1e30f};
  float l_r[4] = {};
  const u16* kgb = kr + (long)bh * T_ * HD_;
  const u16* vgb = vt + (long)bh * HD_ * T_;
  const int kmax = (qt * 64 + 63) >> 7;

  for (int kt = 0; kt <= kmax; kt++){
    __syncthreads();
    const u16* kg = kgb + (long)kt * 128 * HD_;
    #pragma unroll
    for (int c = 0; c < 4; c++){
      int lin = c * 256 + tid, row = lin >> 3, p = lin & 7;
      async16(kg + row * HD_ + ((p ^ (row & 7)) * 8), Ks + lin * 8);
    }
    #pragma unroll
    for (int c = 0; c < 4; c++){
      int lin = c * 256 + tid, row = lin >> 4, p = lin & 15;
      async16(vgb + (long)row * T_ + kt * 128 + ((p ^ (row & 15)) * 8), Vs + lin * 8);
    }
    __syncthreads();

    f32x4 s[8] = {};
    s16x8 aq[2];
    {
      int rA = wrow + fr;
      #pragma unroll
      for (int kk = 0; kk < 2; kk++)
        aq[kk] = *(const s16x8*)(Qs + rA * 64 + (((kk*4 + quad) ^ (rA & 7)) * 8));
    }
    #pragma unroll
    for (int ik = 0; ik < 8; ik++){
      #pragma unroll
      for (int kk = 0; kk < 2; kk++){
        int rB = ik * 16 + fr;
        s16x8 bk = *(const s16x8*)(Ks + rB * 64 + (((kk*4 + quad) ^ (rB & 7)) * 8));
        s[ik] = __builtin_amdgcn_mfma_f32_16x16x32_bf16(aq[kk], bk, s[ik], 0, 0, 0);
      }
    }
    const bool diag = (kt == kmax);
    #pragma unroll
    for (int r = 0; r < 4; r++){
      const int qgi = qt * 64 + wrow + quad * 4 + r;
      float tmax = -1e30f;
      #pragma unroll
      for (int ik = 0; ik < 8; ik++){
        float v = s[ik][r] * 0.125f;
        if (diag && (kt * 128 + ik * 16 + fr) > qgi) v = -1e9f;
        s[ik][r] = v;
        tmax = fmaxf(tmax, v);
      }
      #pragma unroll
      for (int off = 8; off >= 1; off >>= 1) tmax = fmaxf(tmax, __shfl_xor(tmax, off));
      const float mnew = fmaxf(m_r[r], tmax);
      const float alpha = __expf(m_r[r] - mnew);
      m_r[r] = mnew;
      float ts = 0.0f;
      const int prow = wrow + quad * 4 + r;
      #pragma unroll
      for (int ik = 0; ik < 8; ik++){
        float p = __expf(s[ik][r] - mnew);
        ts += p;
        Ps[prow * 136 + ik * 16 + fr] = f2bf(p);
      }
      #pragma unroll
      for (int off = 8; off >= 1; off >>= 1) ts += __shfl_xor(ts, off);
      l_r[r] = l_r[r] * alpha + ts;
      #pragma unroll
      for (int jd = 0; jd < 4; jd++) o_acc[jd][r] *= alpha;
    }
    #pragma unroll
    for (int kk2 = 0; kk2 < 4; kk2++){
      s16x8 ap = *(const s16x8*)(Ps + (wrow + fr) * 136 + kk2 * 32 + quad * 8);
      #pragma unroll
      for (int jd = 0; jd < 4; jd++){
        int rV = jd * 16 + fr;
        s16x8 bv = *(const s16x8*)(Vs + rV * 128 + (((kk2*4 + quad) ^ (rV & 15)) * 8));
        o_acc[jd] = __builtin_amdgcn_mfma_f32_16x16x32_bf16(ap, bv, o_acc[jd], 0, 0, 0);
      }
    }
  }
  #pragma unroll
  for (int r = 0; r < 4; r++){
    const int t_loc = qt * 64 + wrow + quad * 4 + r;
    const long rowbase = ((long)b * T_ + t_loc) * H_ + hh * HD_;
    const float inv = 1.0f / l_r[r];
    #pragma unroll
    for (int jd = 0; jd < 4; jd++)
      att[rowbase + jd * 16 + fr] = f2bf(o_acc[jd][r] * inv);
  }
}

// ---------------------------------------------------------------------------
// Final: h' = h + sum p[0..3]; rms(h',ln_f) @ head_W + b, clamp, softmax/T.
// ---------------------------------------------------------------------------
__global__ __launch_bounds__(256) void head_kernel(
    const float* __restrict__ hsrc, const float* __restrict__ p,
    const float* __restrict__ lnf, const float* __restrict__ hw, const float* __restrict__ hb,
    const float* __restrict__ temp, float* __restrict__ outp)
{
  const int m = blockIdx.x, t = threadIdx.x;
  __shared__ float lat[H_];
  __shared__ float red[4];
  __shared__ float part[8][32];
  float4 v = ((const float4*)(hsrc + (long)m * H_))[t];
  #pragma unroll
  for (int z = 0; z < 4; z++){
    const float4 a = ((const float4*)(p + (long)z * M_ * H_ + (long)m * H_))[t];
    v.x += a.x; v.y += a.y; v.z += a.z; v.w += a.w;
  }
  float ss = v.x*v.x + v.y*v.y + v.z*v.z + v.w*v.w;
  #pragma unroll
  for (int off = 32; off >= 1; off >>= 1) ss += __shfl_xor(ss, off);
  if ((t & 63) == 0) red[t >> 6] = ss;
  __syncthreads();
  const float scale = rsqrtf((red[0]+red[1]+red[2]+red[3]) * (1.0f/H_) + 1e-6f);
  const float4 wv = ((const float4*)lnf)[t];
  lat[t*4+0] = v.x*scale*wv.x;  lat[t*4+1] = v.y*scale*wv.y;
  lat[t*4+2] = v.z*scale*wv.z;  lat[t*4+3] = v.w*scale*wv.w;
  __syncthreads();
  const int j = t & 31, seg = t >> 5;
  float pp = 0.0f;
  if (j < 31){
    const float* wp = hw + j;
    for (int k = seg * 128; k < seg * 128 + 128; k++) pp += lat[k] * wp[(long)k * 31];
  }
  part[seg][j] = pp;
  __syncthreads();
  if (t < 32){
    float dot = 0.0f;
    #pragma unroll
    for (int s2 = 0; s2 < 8; s2++) dot += part[s2][t];
    const float logit = (t < 31) ? dot + hb[t] : -1e30f;
    const float lc = fminf(fmaxf(logit, -10.0f), 10.0f);
    const float z = (t < 31) ? lc / temp[0] : -1e30f;
    float mx = z;
    #pragma unroll
    for (int off = 16; off >= 1; off >>= 1) mx = fmaxf(mx, __shfl_xor(mx, off, 32));
    const float e = (t < 31) ? __expf(z - mx) : 0.0f;
    float sum = e;
    #pragma unroll
    for (int off = 16; off >= 1; off >>= 1) sum += __shfl_xor(sum, off, 32);
    if (t < 31){
      outp[(long)m * NTP1_ + t] = e / sum;
      outp[(long)M_ * NTP1_ + (long)m * NTP1_ + t] = lc;
    }
  }
}

// ---------------------------------------------------------------------------
extern "C" void kernel_launch(void* const* d_in, const int* in_sizes, int n_in,
                              void* d_out, int out_size, void* d_ws, size_t ws_size,
                              hipStream_t stream) {
  const float* x    = (const float*)d_in[0];
  const float* temp = (const float*)d_in[1];
  const float* sW   = (const float*)d_in[2];
  const float* sb   = (const float*)d_in[3];
  const float* ln1  = (const float*)d_in[4];
  const float* ln2  = (const float*)d_in[5];
  const float* Wqkv = (const float*)d_in[6];
  const float* Aqkv = (const float*)d_in[7];
  const float* Bqkv = (const float*)d_in[8];
  const float* Wo   = (const float*)d_in[9];
  const float* Ao   = (const float*)d_in[10];
  const float* Bo   = (const float*)d_in[11];
  const float* Wgu  = (const float*)d_in[12];
  const float* Agu  = (const float*)d_in[13];
  const float* Bgu  = (const float*)d_in[14];
  const float* Wd   = (const float*)d_in[15];
  const float* Ad   = (const float*)d_in[16];
  const float* Bd   = (const float*)d_in[17];
  const float* lnf  = (const float*)d_in[18];
  const float* hW   = (const float*)d_in[19];
  const float* hb   = (const float*)d_in[20];
  float* out = (float*)d_out;

  uint8_t* ws = (uint8_t*)d_ws;
  size_t off = 0;
  auto alloc = [&](size_t bytes) -> void* {
    void* p = ws + off;
    off += (bytes + 255) & ~(size_t)255;
    return p;
  };
  u16*   wt_qkv = (u16*)  alloc((size_t)L_ * 3 * H_ * H_ * 2);
  u16*   wt_o   = (u16*)  alloc((size_t)L_ * H_ * H_ * 2);
  u16*   wt_gu  = (u16*)  alloc((size_t)L_ * 2 * F_ * H_ * 2);
  u16*   wt_d   = (u16*)  alloc((size_t)L_ * H_ * F_ * 2);
  float* h      = (float*)alloc((size_t)M_ * H_ * 4);
  u16*   hn     = (u16*)  alloc((size_t)M_ * H_ * 2);
  u16*   qkvb   = (u16*)  alloc((size_t)3 * M_ * H_ * 2);
  float* p      = (float*)alloc((size_t)4 * M_ * H_ * 4);   // split-K partials p[0..3]
  u16*   qr     = (u16*)  alloc((size_t)M_ * H_ * 2);
  u16*   krr    = (u16*)  alloc((size_t)M_ * H_ * 2);
  u16*   vtb    = (u16*)  alloc((size_t)M_ * H_ * 2);
  u16*   attb   = (u16*)  alloc((size_t)M_ * H_ * 2);
  u16*   actb   = (u16*)  alloc((size_t)M_ * F_ * 2);

  // --- per-launch weight fold+convert+transpose ---
  fold_kernel<<<dim3(16, 16, L_ * 3), 256, 0, stream>>>(Wqkv, Aqkv, Bqkv, wt_qkv,
      H_, H_, (long)H_ * H_, (long)R_ * H_, (long)H_ * R_, (long)H_ * H_);
  fold_kernel<<<dim3(16, 16, L_), 256, 0, stream>>>(Wo, Ao, Bo, wt_o,
      H_, H_, (long)H_ * H_, (long)R_ * H_, (long)H_ * R_, (long)H_ * H_);
  fold_kernel<<<dim3(16, 44, L_ * 2), 256, 0, stream>>>(Wgu, Agu, Bgu, wt_gu,
      H_, F_, (long)H_ * F_, (long)R_ * H_, (long)F_ * R_, (long)F_ * H_);
  fold_kernel<<<dim3(44, 16, L_), 256, 0, stream>>>(Wd, Ad, Bd, wt_d,
      F_, H_, (long)F_ * H_, (long)R_ * F_, (long)H_ * R_, (long)H_ * F_);

  embed_kernel<<<M_, 256, 0, stream>>>(x, sW, sb, h);

  for (int l = 0; l < L_; l++){
    // h += d-partials of previous layer (l>0), then rms -> hn
    rms_kernel<<<M_, 256, 0, stream>>>(h, p, ln1 + (long)l * H_, hn, l > 0 ? 1 : 0);
    // qkv: bf16 out, z=3 mats
    gemm_bt<1><<<dim3(16, 8, 3), 256, 0, stream>>>(hn, wt_qkv + (long)l * 3 * H_ * H_,
        qkvb, H_, H_, H_, 0, (long)H_ * H_, (long)M_ * H_);
    rope_vt_kernel<<<M_ + 1024, 256, 0, stream>>>(qkvb, qr, krr, vtb);
    attn_kernel<<<dim3(T_ / 64, B_ * NH_), 256, 0, stream>>>(qr, krr, vtb, attb);
    // o-proj: split-K=4 partials into p[0..3]  (K chunks of 256)
    gemm_bt<0><<<dim3(16, 8, 4), 256, 0, stream>>>(attb, wt_o + (long)l * H_ * H_,
        p, H_, 256, H_, 256, 256, (long)M_ * H_);
    // h += o-partials, rms -> hn
    rms_kernel<<<M_, 256, 0, stream>>>(h, p, ln2 + (long)l * H_, hn, 1);
    // fused gate/up GEMM + silu -> actb (bf16)
    gemm_gu<<<dim3(16, 22), 256, 0, stream>>>(hn,
        wt_gu + (long)l * 2 * F_ * H_, wt_gu + (long)l * 2 * F_ * H_ + (long)F_ * H_, actb);
    // down-proj: split-K=4 partials into p[0..3]  (K chunks of 704 = 22*32)
    gemm_bt<0><<<dim3(16, 8, 4), 256, 0, stream>>>(actb, wt_d + (long)l * H_ * F_,
        p, H_, 704, F_, 704, 704, (long)M_ * H_);
  }

  head_kernel<<<M_, 256, 0, stream>>>(h, p, lnf, hW, hb, temp, out);
}

// Round 5
// 1741.105 us; speedup vs baseline: 1.0781x; 1.0781x over previous
//
#include <hip/hip_runtime.h>
#include <hip/hip_bf16.h>
#include <cstdint>

// Shapes (compile-time constants for this problem)
#define B_    2
#define T_    1024
#define NT_   30
#define H_    1024
#define L_    8
#define F_    2816
#define NH_   16
#define R_    16
#define HD_   64
#define M_    2048          // B*T
#define NTP1_ 31

typedef unsigned short u16;
typedef short  s16x8 __attribute__((ext_vector_type(8)));   // MFMA bf16 operand
typedef unsigned short u16x4 __attribute__((ext_vector_type(4)));
typedef unsigned short u16x8 __attribute__((ext_vector_type(8)));
typedef float  f32x4 __attribute__((ext_vector_type(4)));

__device__ __forceinline__ u16 f2bf(float f){
  __hip_bfloat16 h = __float2bfloat16(f);
  return __builtin_bit_cast(unsigned short, h);
}
__device__ __forceinline__ float bf2f(u16 u){
  uint32_t v = (uint32_t)u << 16;
  return __builtin_bit_cast(float, v);
}

__device__ __forceinline__ void async16(const void* g, void* l){
  __builtin_amdgcn_global_load_lds((const __attribute__((address_space(1))) void*)g,
                                   (__attribute__((address_space(3))) void*)l, 16, 0, 0);
}

// ---------------------------------------------------------------------------
// Fold LoRA into weights, convert to bf16, TRANSPOSE to Wt[n][k].
// Wt[n][k] = W[k][n] + 2 * sum_r A[r][k] * Bm[n][r]
// ---------------------------------------------------------------------------
__global__ __launch_bounds__(256, 3) void fold_kernel(
    const float* __restrict__ W, const float* __restrict__ A,
    const float* __restrict__ Bm, u16* __restrict__ Wt,
    int K, int N, long strW, long strA, long strB, long strWt)
{
  const int mat = blockIdx.z;
  W  += (long)mat * strW;  A  += (long)mat * strA;
  Bm += (long)mat * strB;  Wt += (long)mat * strWt;
  const int k0 = blockIdx.x * 64, n0 = blockIdx.y * 64;
  __shared__ float Wt_s[64][65];   // [n][k]
  __shared__ float As[16][64];     // [r][k]
  __shared__ float Bs[64][20];     // [n][r]
  const int tid = threadIdx.x;
  {
    const int kr = tid >> 4;
    const int n4 = (tid & 15) * 4;
    #pragma unroll
    for (int p = 0; p < 4; p++){
      int krow = p * 16 + kr;
      float4 w = *(const float4*)(W + (long)(k0 + krow) * N + n0 + n4);
      Wt_s[n4+0][krow] = w.x; Wt_s[n4+1][krow] = w.y;
      Wt_s[n4+2][krow] = w.z; Wt_s[n4+3][krow] = w.w;
    }
    const int r = tid >> 4, kc = (tid & 15) * 4;
    *(float4*)&As[r][kc] = *(const float4*)(A + (long)r * K + k0 + kc);
    const int nb = tid >> 2, r4 = (tid & 3) * 4;
    float4 b = *(const float4*)(Bm + (long)(n0 + nb) * 16 + r4);
    Bs[nb][r4+0]=b.x; Bs[nb][r4+1]=b.y; Bs[nb][r4+2]=b.z; Bs[nb][r4+3]=b.w;
  }
  __syncthreads();
  const int ko = (tid & 7) * 8;
  const int na = tid >> 3;
  float bq0[16], bq1[16];
  #pragma unroll
  for (int c = 0; c < 4; c++){
    *(float4*)&bq0[c*4] = *(const float4*)&Bs[na][c*4];
    *(float4*)&bq1[c*4] = *(const float4*)&Bs[na+32][c*4];
  }
  float l0[8] = {}, l1[8] = {};
  #pragma unroll
  for (int r = 0; r < 16; r++){
    float a[8];
    *(float4*)&a[0] = *(const float4*)&As[r][ko];
    *(float4*)&a[4] = *(const float4*)&As[r][ko+4];
    #pragma unroll
    for (int j = 0; j < 8; j++){
      l0[j] += a[j] * bq0[r];
      l1[j] += a[j] * bq1[r];
    }
  }
  u16x8 o0, o1;
  #pragma unroll
  for (int j = 0; j < 8; j++){
    o0[j] = f2bf(Wt_s[na][ko+j]    + 2.0f * l0[j]);
    o1[j] = f2bf(Wt_s[na+32][ko+j] + 2.0f * l1[j]);
  }
  *(u16x8*)(Wt + (long)(n0+na)*K    + k0 + ko) = o0;
  *(u16x8*)(Wt + (long)(n0+na+32)*K + k0 + ko) = o1;
}

// ---------------------------------------------------------------------------
// h = x @ state_W + state_b.  grid M_, 256 thr.
// ---------------------------------------------------------------------------
__global__ __launch_bounds__(256) void embed_kernel(
    const float* __restrict__ x, const float* __restrict__ sw,
    const float* __restrict__ sb, float* __restrict__ h)
{
  const int m = blockIdx.x;
  const float* xr = x + (long)m * NT_;
  for (int jj = threadIdx.x; jj < H_; jj += 256){
    float acc = sb[jj];
    #pragma unroll
    for (int i = 0; i < NT_; i++) acc += xr[i] * sw[i * H_ + jj];
    h[(long)m * H_ + jj] = acc;
  }
}

// ---------------------------------------------------------------------------
// RMSNorm row -> bf16, optionally fusing h += p0 + p1 (split-K GEMM partials),
// writing h back. grid M_, 256 thr.
// ---------------------------------------------------------------------------
__global__ __launch_bounds__(256) void rms_kernel(
    float* __restrict__ hsrc, const float* __restrict__ p0, const float* __restrict__ p1,
    const float* __restrict__ w, u16* __restrict__ outp, int fuse)
{
  const int m = blockIdx.x, t = threadIdx.x;
  float4 v = ((const float4*)(hsrc + (long)m * H_))[t];
  if (fuse){
    const float4 a = ((const float4*)(p0 + (long)m * H_))[t];
    const float4 b = ((const float4*)(p1 + (long)m * H_))[t];
    v.x += a.x + b.x; v.y += a.y + b.y; v.z += a.z + b.z; v.w += a.w + b.w;
    ((float4*)(hsrc + (long)m * H_))[t] = v;
  }
  float ss = v.x*v.x + v.y*v.y + v.z*v.z + v.w*v.w;
  #pragma unroll
  for (int off = 32; off >= 1; off >>= 1) ss += __shfl_xor(ss, off);
  __shared__ float red[4];
  if ((t & 63) == 0) red[t >> 6] = ss;
  __syncthreads();
  const float scale = rsqrtf((red[0]+red[1]+red[2]+red[3]) * (1.0f/H_) + 1e-6f);
  const float4 wv = ((const float4*)w)[t];
  u16x4 o;
  o[0] = f2bf(v.x*scale*wv.x); o[1] = f2bf(v.y*scale*wv.y);
  o[2] = f2bf(v.z*scale*wv.z); o[3] = f2bf(v.w*scale*wv.w);
  *(u16x4*)(outp + (long)m * H_ + t * 4) = o;
}

// ---------------------------------------------------------------------------
// GEMM: C[m][n] = A(M,K)bf16 @ Bt(N,K)bf16^T.  OUTBF=1 -> bf16 out, 0 -> fp32.
// m97 structure: BK=64, 2-barrier K-loop, global_load_lds width-16 staging.
// Klen = K extent of this launch (split-K), Kstride = row stride of A and Bt.
// grid (M/128, N/128, Z), 256 thr.
// ---------------------------------------------------------------------------
template<int OUTBF>
__global__ __launch_bounds__(256, 2) void gemm_bt(
    const u16* __restrict__ Ag, const u16* __restrict__ Btg, void* __restrict__ Cptr,
    int Ndim, int Klen, int Kstride, long zsA, long zsB, long zsC)
{
  Ag  += (long)blockIdx.z * zsA;
  Btg += (long)blockIdx.z * zsB;
  const int m0 = blockIdx.x * 128, n0 = blockIdx.y * 128;
  __shared__ alignas(16) u16 As[128 * 64];
  __shared__ alignas(16) u16 Bs[128 * 64];
  const int tid = threadIdx.x;
  const int wave = tid >> 6, lane = tid & 63;
  const int wm = (wave & 1) * 64, wn = (wave >> 1) * 64;
  const int fr = lane & 15, quad = lane >> 4;

  f32x4 acc[4][4] = {};

  for (int kt = 0; kt < Klen; kt += 64){
    __syncthreads();
    #pragma unroll
    for (int c = 0; c < 4; c++){
      int lin = c * 256 + tid;
      int row = lin >> 3, p = lin & 7;
      int gc = ((p ^ (row & 7)) * 8);
      async16(Ag  + (long)(m0 + row) * Kstride + kt + gc, As + lin * 8);
      async16(Btg + (long)(n0 + row) * Kstride + kt + gc, Bs + lin * 8);
    }
    __syncthreads();
    #pragma unroll
    for (int kk = 0; kk < 2; kk++){
      s16x8 af[4], bg[4];
      #pragma unroll
      for (int i = 0; i < 4; i++){
        int rA = wm + i * 16 + fr;
        af[i] = *(const s16x8*)(As + rA * 64 + (((kk*4 + quad) ^ (rA & 7)) * 8));
        int rB = wn + i * 16 + fr;
        bg[i] = *(const s16x8*)(Bs + rB * 64 + (((kk*4 + quad) ^ (rB & 7)) * 8));
      }
      #pragma unroll
      for (int i = 0; i < 4; i++)
        #pragma unroll
        for (int j = 0; j < 4; j++)
          acc[i][j] = __builtin_amdgcn_mfma_f32_16x16x32_bf16(af[i], bg[j], acc[i][j], 0, 0, 0);
    }
  }
  #pragma unroll
  for (int i = 0; i < 4; i++){
    int row0 = m0 + wm + i * 16 + quad * 4;
    #pragma unroll
    for (int j = 0; j < 4; j++){
      int col = n0 + wn + j * 16 + fr;
      #pragma unroll
      for (int r = 0; r < 4; r++){
        long idx = (long)(row0 + r) * Ndim + col;
        if (OUTBF){
          u16* C = (u16*)Cptr + (long)blockIdx.z * zsC;
          C[idx] = f2bf(acc[i][j][r]);
        } else {
          float* C = (float*)Cptr + (long)blockIdx.z * zsC;
          C[idx] = acc[i][j][r];
        }
      }
    }
  }
}

// ---------------------------------------------------------------------------
// Fused gate/up GEMM + SiLU: act[m][n] = silu(A@Wg^T) * (A@Wu^T), bf16 out.
// A (M,1024) bf16, Wg/Wu (F,1024) bf16. grid (M/128, F/128), 256 thr.
// ---------------------------------------------------------------------------
__global__ __launch_bounds__(256, 2) void gemm_gu(
    const u16* __restrict__ Ag, const u16* __restrict__ Bgw,
    const u16* __restrict__ Buw, u16* __restrict__ actb)
{
  const int m0 = blockIdx.x * 128, n0 = blockIdx.y * 128;
  __shared__ alignas(16) u16 As[128 * 64];
  __shared__ alignas(16) u16 Bg_[128 * 64];
  __shared__ alignas(16) u16 Bu_[128 * 64];
  const int tid = threadIdx.x;
  const int wave = tid >> 6, lane = tid & 63;
  const int wm = (wave & 1) * 64, wn = (wave >> 1) * 64;
  const int fr = lane & 15, quad = lane >> 4;

  f32x4 accg[4][4] = {}, accu[4][4] = {};

  for (int kt = 0; kt < H_; kt += 64){
    __syncthreads();
    #pragma unroll
    for (int c = 0; c < 4; c++){
      int lin = c * 256 + tid;
      int row = lin >> 3, p = lin & 7;
      int gc = ((p ^ (row & 7)) * 8);
      async16(Ag  + (long)(m0 + row) * H_ + kt + gc, As  + lin * 8);
      async16(Bgw + (long)(n0 + row) * H_ + kt + gc, Bg_ + lin * 8);
      async16(Buw + (long)(n0 + row) * H_ + kt + gc, Bu_ + lin * 8);
    }
    __syncthreads();
    #pragma unroll
    for (int kk = 0; kk < 2; kk++){
      s16x8 af[4], bb[4];
      #pragma unroll
      for (int i = 0; i < 4; i++){
        int rA = wm + i * 16 + fr;
        af[i] = *(const s16x8*)(As + rA * 64 + (((kk*4 + quad) ^ (rA & 7)) * 8));
      }
      #pragma unroll
      for (int i = 0; i < 4; i++){
        int rB = wn + i * 16 + fr;
        bb[i] = *(const s16x8*)(Bg_ + rB * 64 + (((kk*4 + quad) ^ (rB & 7)) * 8));
      }
      #pragma unroll
      for (int i = 0; i < 4; i++)
        #pragma unroll
        for (int j = 0; j < 4; j++)
          accg[i][j] = __builtin_amdgcn_mfma_f32_16x16x32_bf16(af[i], bb[j], accg[i][j], 0, 0, 0);
      #pragma unroll
      for (int i = 0; i < 4; i++){
        int rB = wn + i * 16 + fr;
        bb[i] = *(const s16x8*)(Bu_ + rB * 64 + (((kk*4 + quad) ^ (rB & 7)) * 8));
      }
      #pragma unroll
      for (int i = 0; i < 4; i++)
        #pragma unroll
        for (int j = 0; j < 4; j++)
          accu[i][j] = __builtin_amdgcn_mfma_f32_16x16x32_bf16(af[i], bb[j], accu[i][j], 0, 0, 0);
    }
  }
  #pragma unroll
  for (int i = 0; i < 4; i++){
    int row0 = m0 + wm + i * 16 + quad * 4;
    #pragma unroll
    for (int j = 0; j < 4; j++){
      int col = n0 + wn + j * 16 + fr;
      #pragma unroll
      for (int r = 0; r < 4; r++){
        float g = accg[i][j][r], u = accu[i][j][r];
        float act = g / (1.0f + __expf(-g)) * u;
        actb[(long)(row0 + r) * F_ + col] = f2bf(act);
      }
    }
  }
}

// ---------------------------------------------------------------------------
// Merged RoPE + V-transpose, reading qkv split-K partials (fp32, two halves).
// pq layout: [z][m][n'] with n' in [0,3072): 0..1023 q, 1024..2047 k, 2048.. v.
// Blocks [0, M_): rope for one (b,t). Blocks [M_, M_+1024): vtrans.
// ---------------------------------------------------------------------------
__global__ __launch_bounds__(256) void rope_vt_kernel(
    const float* __restrict__ pq, u16* __restrict__ qr, u16* __restrict__ kr,
    u16* __restrict__ vt)
{
  const int bid = blockIdx.x;
  if (bid < M_){
    const int m = bid;
    const int b = m >> 10, t = m & 1023;
    for (int w = threadIdx.x; w < 1024; w += 256){
      const int sel = w >> 9;          // 0=q 1=k
      const int hh  = (w >> 5) & 15;
      const int i   = w & 31;
      const float* s0 = pq + (long)m * 3072 + sel * 1024 + hh * HD_;
      const float* s1 = s0 + (long)M_ * 3072;
      float x1 = s0[i] + s1[i];
      float x2 = s0[i + 32] + s1[i + 32];
      float freq = exp2f((float)i * (-13.287712379549449f / 32.0f)); // 10000^(-i/32)
      float ang = (float)t * freq;
      float sn, cs; __sincosf(ang, &sn, &cs);
      u16* dst = (sel ? kr : qr) + ((long)((b * NH_ + hh) * T_ + t)) * HD_;
      dst[i]      = f2bf(x1 * cs - x2 * sn);
      dst[i + 32] = f2bf(x2 * cs + x1 * sn);
    }
  } else {
    const int v = bid - M_;            // 0..1023
    const int bh = v >> 5, tch = v & 31;
    const int b = bh >> 4, hh = bh & 15;
    const int d = threadIdx.x & 63, tc = threadIdx.x >> 6;
    const int t0 = tch * 32 + tc * 8;
    u16x8 o;
    #pragma unroll
    for (int j = 0; j < 8; j++){
      long idx = (long)(b * T_ + t0 + j) * 3072 + 2048 + hh * HD_ + d;
      o[j] = f2bf(pq[idx] + pq[idx + (long)M_ * 3072]);
    }
    *(u16x8*)(vt + ((long)bh * HD_ + d) * T_ + t0) = o;
  }
}

// ---------------------------------------------------------------------------
// Flash attention, causal-balanced: grid (8, B_*NH_), 256 thr.
// Each block processes q-tiles qt and 15-qt (uniform 9 k-tile units/block).
// ---------------------------------------------------------------------------
__global__ __launch_bounds__(256, 2) void attn_kernel(
    const u16* __restrict__ qr, const u16* __restrict__ kr,
    const u16* __restrict__ vt, u16* __restrict__ att)
{
  const int bh = blockIdx.y;
  const int b = bh >> 4, hh = bh & 15;
  __shared__ alignas(16) u16 Qs[64 * 64];
  __shared__ alignas(16) u16 Ks[128 * 64];
  __shared__ alignas(16) u16 Vs[64 * 128];
  __shared__ alignas(16) u16 Ps[64 * 136];
  const int tid = threadIdx.x;
  const int wave = tid >> 6, lane = tid & 63, fr = lane & 15, quad = lane >> 4;
  const int wrow = wave * 16;
  const u16* kgb = kr + (long)bh * T_ * HD_;
  const u16* vgb = vt + (long)bh * HD_ * T_;

  for (int pass = 0; pass < 2; pass++){
    const int qt = pass ? (15 - (int)blockIdx.x) : (int)blockIdx.x;
    __syncthreads();   // guard Qs/Ks/Vs/Ps reuse across passes
    const u16* qg = qr + ((long)bh * T_ + qt * 64) * HD_;
    #pragma unroll
    for (int c = 0; c < 2; c++){
      int lin = c * 256 + tid, row = lin >> 3, p = lin & 7;
      async16(qg + row * HD_ + ((p ^ (row & 7)) * 8), Qs + lin * 8);
    }
    f32x4 o_acc[4] = {};
    float m_r[4] = {-1e30f, -1e30f, -1e30f, -1e30f};
    float l_r[4] = {};
    const int kmax = (qt * 64 + 63) >> 7;

    for (int kt = 0; kt <= kmax; kt++){
      __syncthreads();
      const u16* kg = kgb + (long)kt * 128 * HD_;
      #pragma unroll
      for (int c = 0; c < 4; c++){
        int lin = c * 256 + tid, row = lin >> 3, p = lin & 7;
        async16(kg + row * HD_ + ((p ^ (row & 7)) * 8), Ks + lin * 8);
      }
      #pragma unroll
      for (int c = 0; c < 4; c++){
        int lin = c * 256 + tid, row = lin >> 4, p = lin & 15;
        async16(vgb + (long)row * T_ + kt * 128 + ((p ^ (row & 15)) * 8), Vs + lin * 8);
      }
      __syncthreads();

      f32x4 s[8] = {};
      s16x8 aq[2];
      {
        int rA = wrow + fr;
        #pragma unroll
        for (int kk = 0; kk < 2; kk++)
          aq[kk] = *(const s16x8*)(Qs + rA * 64 + (((kk*4 + quad) ^ (rA & 7)) * 8));
      }
      #pragma unroll
      for (int ik = 0; ik < 8; ik++){
        #pragma unroll
        for (int kk = 0; kk < 2; kk++){
          int rB = ik * 16 + fr;
          s16x8 bk = *(const s16x8*)(Ks + rB * 64 + (((kk*4 + quad) ^ (rB & 7)) * 8));
          s[ik] = __builtin_amdgcn_mfma_f32_16x16x32_bf16(aq[kk], bk, s[ik], 0, 0, 0);
        }
      }
      const bool diag = (kt == kmax);
      #pragma unroll
      for (int r = 0; r < 4; r++){
        const int qgi = qt * 64 + wrow + quad * 4 + r;
        float tmax = -1e30f;
        #pragma unroll
        for (int ik = 0; ik < 8; ik++){
          float v = s[ik][r] * 0.125f;
          if (diag && (kt * 128 + ik * 16 + fr) > qgi) v = -1e9f;
          s[ik][r] = v;
          tmax = fmaxf(tmax, v);
        }
        #pragma unroll
        for (int off = 8; off >= 1; off >>= 1) tmax = fmaxf(tmax, __shfl_xor(tmax, off));
        const float mnew = fmaxf(m_r[r], tmax);
        const float alpha = __expf(m_r[r] - mnew);
        m_r[r] = mnew;
        float ts = 0.0f;
        const int prow = wrow + quad * 4 + r;
        #pragma unroll
        for (int ik = 0; ik < 8; ik++){
          float p = __expf(s[ik][r] - mnew);
          ts += p;
          Ps[prow * 136 + ik * 16 + fr] = f2bf(p);
        }
        #pragma unroll
        for (int off = 8; off >= 1; off >>= 1) ts += __shfl_xor(ts, off);
        l_r[r] = l_r[r] * alpha + ts;
        #pragma unroll
        for (int jd = 0; jd < 4; jd++) o_acc[jd][r] *= alpha;
      }
      #pragma unroll
      for (int kk2 = 0; kk2 < 4; kk2++){
        s16x8 ap = *(const s16x8*)(Ps + (wrow + fr) * 136 + kk2 * 32 + quad * 8);
        #pragma unroll
        for (int jd = 0; jd < 4; jd++){
          int rV = jd * 16 + fr;
          s16x8 bv = *(const s16x8*)(Vs + rV * 128 + (((kk2*4 + quad) ^ (rV & 15)) * 8));
          o_acc[jd] = __builtin_amdgcn_mfma_f32_16x16x32_bf16(ap, bv, o_acc[jd], 0, 0, 0);
        }
      }
    }
    #pragma unroll
    for (int r = 0; r < 4; r++){
      const int t_loc = qt * 64 + wrow + quad * 4 + r;
      const long rowbase = ((long)b * T_ + t_loc) * H_ + hh * HD_;
      const float inv = 1.0f / l_r[r];
      #pragma unroll
      for (int jd = 0; jd < 4; jd++)
        att[rowbase + jd * 16 + fr] = f2bf(o_acc[jd][r] * inv);
    }
  }
}

// ---------------------------------------------------------------------------
// Final: h' = h + p0 + p1; rms(h',ln_f) @ head_W + b, clamp, softmax/T.
// grid M_, 256 thr. out = [weights (M_*31), logits (M_*31)]
// ---------------------------------------------------------------------------
__global__ __launch_bounds__(256) void head_kernel(
    const float* __restrict__ hsrc, const float* __restrict__ p0, const float* __restrict__ p1,
    const float* __restrict__ lnf, const float* __restrict__ hw, const float* __restrict__ hb,
    const float* __restrict__ temp, float* __restrict__ outp)
{
  const int m = blockIdx.x, t = threadIdx.x;
  __shared__ float lat[H_];
  __shared__ float red[4];
  __shared__ float part[8][32];
  float4 v = ((const float4*)(hsrc + (long)m * H_))[t];
  {
    const float4 a = ((const float4*)(p0 + (long)m * H_))[t];
    const float4 b = ((const float4*)(p1 + (long)m * H_))[t];
    v.x += a.x + b.x; v.y += a.y + b.y; v.z += a.z + b.z; v.w += a.w + b.w;
  }
  float ss = v.x*v.x + v.y*v.y + v.z*v.z + v.w*v.w;
  #pragma unroll
  for (int off = 32; off >= 1; off >>= 1) ss += __shfl_xor(ss, off);
  if ((t & 63) == 0) red[t >> 6] = ss;
  __syncthreads();
  const float scale = rsqrtf((red[0]+red[1]+red[2]+red[3]) * (1.0f/H_) + 1e-6f);
  const float4 wv = ((const float4*)lnf)[t];
  lat[t*4+0] = v.x*scale*wv.x;  lat[t*4+1] = v.y*scale*wv.y;
  lat[t*4+2] = v.z*scale*wv.z;  lat[t*4+3] = v.w*scale*wv.w;
  __syncthreads();
  const int j = t & 31, seg = t >> 5;
  float pp = 0.0f;
  if (j < 31){
    const float* wp = hw + j;
    for (int k = seg * 128; k < seg * 128 + 128; k++) pp += lat[k] * wp[(long)k * 31];
  }
  part[seg][j] = pp;
  __syncthreads();
  if (t < 32){
    float dot = 0.0f;
    #pragma unroll
    for (int s2 = 0; s2 < 8; s2++) dot += part[s2][t];
    const float logit = (t < 31) ? dot + hb[t] : -1e30f;
    const float lc = fminf(fmaxf(logit, -10.0f), 10.0f);
    const float z = (t < 31) ? lc / temp[0] : -1e30f;
    float mx = z;
    #pragma unroll
    for (int off = 16; off >= 1; off >>= 1) mx = fmaxf(mx, __shfl_xor(mx, off, 32));
    const float e = (t < 31) ? __expf(z - mx) : 0.0f;
    float sum = e;
    #pragma unroll
    for (int off = 16; off >= 1; off >>= 1) sum += __shfl_xor(sum, off, 32);
    if (t < 31){
      outp[(long)m * NTP1_ + t] = e / sum;
      outp[(long)M_ * NTP1_ + (long)m * NTP1_ + t] = lc;
    }
  }
}

// ---------------------------------------------------------------------------
extern "C" void kernel_launch(void* const* d_in, const int* in_sizes, int n_in,
                              void* d_out, int out_size, void* d_ws, size_t ws_size,
                              hipStream_t stream) {
  const float* x    = (const float*)d_in[0];
  const float* temp = (const float*)d_in[1];
  const float* sW   = (const float*)d_in[2];
  const float* sb   = (const float*)d_in[3];
  const float* ln1  = (const float*)d_in[4];
  const float* ln2  = (const float*)d_in[5];
  const float* Wqkv = (const float*)d_in[6];
  const float* Aqkv = (const float*)d_in[7];
  const float* Bqkv = (const float*)d_in[8];
  const float* Wo   = (const float*)d_in[9];
  const float* Ao   = (const float*)d_in[10];
  const float* Bo   = (const float*)d_in[11];
  const float* Wgu  = (const float*)d_in[12];
  const float* Agu  = (const float*)d_in[13];
  const float* Bgu  = (const float*)d_in[14];
  const float* Wd   = (const float*)d_in[15];
  const float* Ad   = (const float*)d_in[16];
  const float* Bd   = (const float*)d_in[17];
  const float* lnf  = (const float*)d_in[18];
  const float* hW   = (const float*)d_in[19];
  const float* hb   = (const float*)d_in[20];
  float* out = (float*)d_out;

  uint8_t* ws = (uint8_t*)d_ws;
  size_t off = 0;
  auto alloc = [&](size_t bytes) -> void* {
    void* p = ws + off;
    off += (bytes + 255) & ~(size_t)255;
    return p;
  };
  u16*   wt_qkv = (u16*)  alloc((size_t)L_ * 3 * H_ * H_ * 2);
  u16*   wt_o   = (u16*)  alloc((size_t)L_ * H_ * H_ * 2);
  u16*   wt_gu  = (u16*)  alloc((size_t)L_ * 2 * F_ * H_ * 2);
  u16*   wt_d   = (u16*)  alloc((size_t)L_ * H_ * F_ * 2);
  float* h      = (float*)alloc((size_t)M_ * H_ * 4);
  u16*   hn     = (u16*)  alloc((size_t)M_ * H_ * 2);
  float* pq     = (float*)alloc((size_t)2 * M_ * 3072 * 4); // qkv split-K partials
  float* p0     = (float*)alloc((size_t)2 * M_ * H_ * 4);   // o/d split-K partials
  float* p1     = p0 + (size_t)M_ * H_;
  u16*   qr     = (u16*)  alloc((size_t)M_ * H_ * 2);
  u16*   krr    = (u16*)  alloc((size_t)M_ * H_ * 2);
  u16*   vtb    = (u16*)  alloc((size_t)M_ * H_ * 2);
  u16*   attb   = (u16*)  alloc((size_t)M_ * H_ * 2);
  u16*   actb   = (u16*)  alloc((size_t)M_ * F_ * 2);

  // --- per-launch weight fold+convert+transpose ---
  fold_kernel<<<dim3(16, 16, L_ * 3), 256, 0, stream>>>(Wqkv, Aqkv, Bqkv, wt_qkv,
      H_, H_, (long)H_ * H_, (long)R_ * H_, (long)H_ * R_, (long)H_ * H_);
  fold_kernel<<<dim3(16, 16, L_), 256, 0, stream>>>(Wo, Ao, Bo, wt_o,
      H_, H_, (long)H_ * H_, (long)R_ * H_, (long)H_ * R_, (long)H_ * H_);
  fold_kernel<<<dim3(16, 44, L_ * 2), 256, 0, stream>>>(Wgu, Agu, Bgu, wt_gu,
      H_, F_, (long)H_ * F_, (long)R_ * H_, (long)F_ * R_, (long)F_ * H_);
  fold_kernel<<<dim3(44, 16, L_), 256, 0, stream>>>(Wd, Ad, Bd, wt_d,
      F_, H_, (long)F_ * H_, (long)R_ * F_, (long)H_ * R_, (long)H_ * F_);

  embed_kernel<<<M_, 256, 0, stream>>>(x, sW, sb, h);

  for (int l = 0; l < L_; l++){
    // h += d-partials of previous layer (l>0), then rms -> hn
    rms_kernel<<<M_, 256, 0, stream>>>(h, p0, p1, ln1 + (long)l * H_, hn, l > 0 ? 1 : 0);
    // qkv: N=3072 (3 mats contiguous as (3072,1024)), split-K=2 fp32 partials
    gemm_bt<0><<<dim3(16, 24, 2), 256, 0, stream>>>(hn, wt_qkv + (long)l * 3 * H_ * H_,
        pq, 3072, 512, H_, 512, 512, (long)M_ * 3072);
    rope_vt_kernel<<<M_ + 1024, 256, 0, stream>>>(pq, qr, krr, vtb);
    attn_kernel<<<dim3(8, B_ * NH_), 256, 0, stream>>>(qr, krr, vtb, attb);
    // o-proj: split-K=2 partials into p0/p1
    gemm_bt<0><<<dim3(16, 8, 2), 256, 0, stream>>>(attb, wt_o + (long)l * H_ * H_,
        p0, H_, 512, H_, 512, 512, (long)M_ * H_);
    // h += o-partials, rms -> hn
    rms_kernel<<<M_, 256, 0, stream>>>(h, p0, p1, ln2 + (long)l * H_, hn, 1);
    // fused gate/up GEMM + silu -> actb (bf16)
    gemm_gu<<<dim3(16, 22), 256, 0, stream>>>(hn,
        wt_gu + (long)l * 2 * F_ * H_, wt_gu + (long)l * 2 * F_ * H_ + (long)F_ * H_, actb);
    // down-proj: split-K=2 partials into p0/p1
    gemm_bt<0><<<dim3(16, 8, 2), 256, 0, stream>>>(actb, wt_d + (long)l * H_ * F_,
        p0, H_, 1408, F_, 1408, 1408, (long)M_ * H_);
  }

  head_kernel<<<M_, 256, 0, stream>>>(h, p0, p1, lnf, hW, hb, temp, out);
}

// Round 6
// 1683.548 us; speedup vs baseline: 1.1149x; 1.0342x over previous
//
#include <hip/hip_runtime.h>
#include <hip/hip_bf16.h>
#include <cstdint>

// Shapes (compile-time constants for this problem)
#define B_    2
#define T_    1024
#define NT_   30
#define H_    1024
#define L_    8
#define F_    2816
#define NH_   16
#define R_    16
#define HD_   64
#define M_    2048          // B*T
#define NTP1_ 31

typedef unsigned short u16;
typedef short  s16x8 __attribute__((ext_vector_type(8)));   // MFMA bf16 operand
typedef unsigned short u16x4 __attribute__((ext_vector_type(4)));
typedef unsigned short u16x8 __attribute__((ext_vector_type(8)));
typedef float  f32x4 __attribute__((ext_vector_type(4)));

__device__ __forceinline__ u16 f2bf(float f){
  __hip_bfloat16 h = __float2bfloat16(f);
  return __builtin_bit_cast(unsigned short, h);
}
__device__ __forceinline__ float bf2f(u16 u){
  uint32_t v = (uint32_t)u << 16;
  return __builtin_bit_cast(float, v);
}

__device__ __forceinline__ void async16(const void* g, void* l){
  __builtin_amdgcn_global_load_lds((const __attribute__((address_space(1))) void*)g,
                                   (__attribute__((address_space(3))) void*)l, 16, 0, 0);
}

// ---------------------------------------------------------------------------
// Fold LoRA into weights, convert to bf16, TRANSPOSE to Wt[n][k].
// Wt[n][k] = W[k][n] + 2 * sum_r A[r][k] * Bm[n][r]
// ---------------------------------------------------------------------------
__global__ __launch_bounds__(256, 3) void fold_kernel(
    const float* __restrict__ W, const float* __restrict__ A,
    const float* __restrict__ Bm, u16* __restrict__ Wt,
    int K, int N, long strW, long strA, long strB, long strWt)
{
  const int mat = blockIdx.z;
  W  += (long)mat * strW;  A  += (long)mat * strA;
  Bm += (long)mat * strB;  Wt += (long)mat * strWt;
  const int k0 = blockIdx.x * 64, n0 = blockIdx.y * 64;
  __shared__ float Wt_s[64][65];   // [n][k]
  __shared__ float As[16][64];     // [r][k]
  __shared__ float Bs[64][20];     // [n][r]
  const int tid = threadIdx.x;
  {
    const int kr = tid >> 4;
    const int n4 = (tid & 15) * 4;
    #pragma unroll
    for (int p = 0; p < 4; p++){
      int krow = p * 16 + kr;
      float4 w = *(const float4*)(W + (long)(k0 + krow) * N + n0 + n4);
      Wt_s[n4+0][krow] = w.x; Wt_s[n4+1][krow] = w.y;
      Wt_s[n4+2][krow] = w.z; Wt_s[n4+3][krow] = w.w;
    }
    const int r = tid >> 4, kc = (tid & 15) * 4;
    *(float4*)&As[r][kc] = *(const float4*)(A + (long)r * K + k0 + kc);
    const int nb = tid >> 2, r4 = (tid & 3) * 4;
    float4 b = *(const float4*)(Bm + (long)(n0 + nb) * 16 + r4);
    Bs[nb][r4+0]=b.x; Bs[nb][r4+1]=b.y; Bs[nb][r4+2]=b.z; Bs[nb][r4+3]=b.w;
  }
  __syncthreads();
  const int ko = (tid & 7) * 8;
  const int na = tid >> 3;
  float bq0[16], bq1[16];
  #pragma unroll
  for (int c = 0; c < 4; c++){
    *(float4*)&bq0[c*4] = *(const float4*)&Bs[na][c*4];
    *(float4*)&bq1[c*4] = *(const float4*)&Bs[na+32][c*4];
  }
  float l0[8] = {}, l1[8] = {};
  #pragma unroll
  for (int r = 0; r < 16; r++){
    float a[8];
    *(float4*)&a[0] = *(const float4*)&As[r][ko];
    *(float4*)&a[4] = *(const float4*)&As[r][ko+4];
    #pragma unroll
    for (int j = 0; j < 8; j++){
      l0[j] += a[j] * bq0[r];
      l1[j] += a[j] * bq1[r];
    }
  }
  u16x8 o0, o1;
  #pragma unroll
  for (int j = 0; j < 8; j++){
    o0[j] = f2bf(Wt_s[na][ko+j]    + 2.0f * l0[j]);
    o1[j] = f2bf(Wt_s[na+32][ko+j] + 2.0f * l1[j]);
  }
  *(u16x8*)(Wt + (long)(n0+na)*K    + k0 + ko) = o0;
  *(u16x8*)(Wt + (long)(n0+na+32)*K + k0 + ko) = o1;
}

// ---------------------------------------------------------------------------
// h = x @ state_W + state_b.  grid M_, 256 thr.
// ---------------------------------------------------------------------------
__global__ __launch_bounds__(256) void embed_kernel(
    const float* __restrict__ x, const float* __restrict__ sw,
    const float* __restrict__ sb, float* __restrict__ h)
{
  const int m = blockIdx.x;
  const float* xr = x + (long)m * NT_;
  for (int jj = threadIdx.x; jj < H_; jj += 256){
    float acc = sb[jj];
    #pragma unroll
    for (int i = 0; i < NT_; i++) acc += xr[i] * sw[i * H_ + jj];
    h[(long)m * H_ + jj] = acc;
  }
}

// ---------------------------------------------------------------------------
// RMSNorm row -> bf16, optionally fusing h += p0 + p1 (split-K GEMM partials),
// writing h back. grid M_, 256 thr.
// ---------------------------------------------------------------------------
__global__ __launch_bounds__(256) void rms_kernel(
    float* __restrict__ hsrc, const float* __restrict__ p0, const float* __restrict__ p1,
    const float* __restrict__ w, u16* __restrict__ outp, int fuse)
{
  const int m = blockIdx.x, t = threadIdx.x;
  float4 v = ((const float4*)(hsrc + (long)m * H_))[t];
  if (fuse){
    const float4 a = ((const float4*)(p0 + (long)m * H_))[t];
    const float4 b = ((const float4*)(p1 + (long)m * H_))[t];
    v.x += a.x + b.x; v.y += a.y + b.y; v.z += a.z + b.z; v.w += a.w + b.w;
    ((float4*)(hsrc + (long)m * H_))[t] = v;
  }
  float ss = v.x*v.x + v.y*v.y + v.z*v.z + v.w*v.w;
  #pragma unroll
  for (int off = 32; off >= 1; off >>= 1) ss += __shfl_xor(ss, off);
  __shared__ float red[4];
  if ((t & 63) == 0) red[t >> 6] = ss;
  __syncthreads();
  const float scale = rsqrtf((red[0]+red[1]+red[2]+red[3]) * (1.0f/H_) + 1e-6f);
  const float4 wv = ((const float4*)w)[t];
  u16x4 o;
  o[0] = f2bf(v.x*scale*wv.x); o[1] = f2bf(v.y*scale*wv.y);
  o[2] = f2bf(v.z*scale*wv.z); o[3] = f2bf(v.w*scale*wv.w);
  *(u16x4*)(outp + (long)m * H_ + t * 4) = o;
}

// ---------------------------------------------------------------------------
// GEMM: C[m][n] = A(M,K)bf16 @ Bt(N,K)bf16^T.  OUTBF=1 -> bf16 out, 0 -> fp32.
// m97 structure: BK=64, 2-barrier K-loop, global_load_lds width-16 staging.
// Klen = K extent of this launch (split-K), Kstride = row stride of A and Bt.
// grid (M/128, N/128, Z), 256 thr.
// ---------------------------------------------------------------------------
template<int OUTBF>
__global__ __launch_bounds__(256, 2) void gemm_bt(
    const u16* __restrict__ Ag, const u16* __restrict__ Btg, void* __restrict__ Cptr,
    int Ndim, int Klen, int Kstride, long zsA, long zsB, long zsC)
{
  Ag  += (long)blockIdx.z * zsA;
  Btg += (long)blockIdx.z * zsB;
  const int m0 = blockIdx.x * 128, n0 = blockIdx.y * 128;
  __shared__ alignas(16) u16 As[128 * 64];
  __shared__ alignas(16) u16 Bs[128 * 64];
  const int tid = threadIdx.x;
  const int wave = tid >> 6, lane = tid & 63;
  const int wm = (wave & 1) * 64, wn = (wave >> 1) * 64;
  const int fr = lane & 15, quad = lane >> 4;

  f32x4 acc[4][4] = {};

  for (int kt = 0; kt < Klen; kt += 64){
    __syncthreads();
    #pragma unroll
    for (int c = 0; c < 4; c++){
      int lin = c * 256 + tid;
      int row = lin >> 3, p = lin & 7;
      int gc = ((p ^ (row & 7)) * 8);
      async16(Ag  + (long)(m0 + row) * Kstride + kt + gc, As + lin * 8);
      async16(Btg + (long)(n0 + row) * Kstride + kt + gc, Bs + lin * 8);
    }
    __syncthreads();
    #pragma unroll
    for (int kk = 0; kk < 2; kk++){
      s16x8 af[4], bg[4];
      #pragma unroll
      for (int i = 0; i < 4; i++){
        int rA = wm + i * 16 + fr;
        af[i] = *(const s16x8*)(As + rA * 64 + (((kk*4 + quad) ^ (rA & 7)) * 8));
        int rB = wn + i * 16 + fr;
        bg[i] = *(const s16x8*)(Bs + rB * 64 + (((kk*4 + quad) ^ (rB & 7)) * 8));
      }
      #pragma unroll
      for (int i = 0; i < 4; i++)
        #pragma unroll
        for (int j = 0; j < 4; j++)
          acc[i][j] = __builtin_amdgcn_mfma_f32_16x16x32_bf16(af[i], bg[j], acc[i][j], 0, 0, 0);
    }
  }
  #pragma unroll
  for (int i = 0; i < 4; i++){
    int row0 = m0 + wm + i * 16 + quad * 4;
    #pragma unroll
    for (int j = 0; j < 4; j++){
      int col = n0 + wn + j * 16 + fr;
      #pragma unroll
      for (int r = 0; r < 4; r++){
        long idx = (long)(row0 + r) * Ndim + col;
        if (OUTBF){
          u16* C = (u16*)Cptr + (long)blockIdx.z * zsC;
          C[idx] = f2bf(acc[i][j][r]);
        } else {
          float* C = (float*)Cptr + (long)blockIdx.z * zsC;
          C[idx] = acc[i][j][r];
        }
      }
    }
  }
}

// ---------------------------------------------------------------------------
// Fused gate/up GEMM + SiLU: act[m][n] = silu(A@Wg^T) * (A@Wu^T), bf16 out.
// A (M,1024) bf16, Wg/Wu (F,1024) bf16. grid (M/128, F/128), 256 thr.
// ---------------------------------------------------------------------------
__global__ __launch_bounds__(256, 2) void gemm_gu(
    const u16* __restrict__ Ag, const u16* __restrict__ Bgw,
    const u16* __restrict__ Buw, u16* __restrict__ actb)
{
  const int m0 = blockIdx.x * 128, n0 = blockIdx.y * 128;
  __shared__ alignas(16) u16 As[128 * 64];
  __shared__ alignas(16) u16 Bg_[128 * 64];
  __shared__ alignas(16) u16 Bu_[128 * 64];
  const int tid = threadIdx.x;
  const int wave = tid >> 6, lane = tid & 63;
  const int wm = (wave & 1) * 64, wn = (wave >> 1) * 64;
  const int fr = lane & 15, quad = lane >> 4;

  f32x4 accg[4][4] = {}, accu[4][4] = {};

  for (int kt = 0; kt < H_; kt += 64){
    __syncthreads();
    #pragma unroll
    for (int c = 0; c < 4; c++){
      int lin = c * 256 + tid;
      int row = lin >> 3, p = lin & 7;
      int gc = ((p ^ (row & 7)) * 8);
      async16(Ag  + (long)(m0 + row) * H_ + kt + gc, As  + lin * 8);
      async16(Bgw + (long)(n0 + row) * H_ + kt + gc, Bg_ + lin * 8);
      async16(Buw + (long)(n0 + row) * H_ + kt + gc, Bu_ + lin * 8);
    }
    __syncthreads();
    #pragma unroll
    for (int kk = 0; kk < 2; kk++){
      s16x8 af[4], bb[4];
      #pragma unroll
      for (int i = 0; i < 4; i++){
        int rA = wm + i * 16 + fr;
        af[i] = *(const s16x8*)(As + rA * 64 + (((kk*4 + quad) ^ (rA & 7)) * 8));
      }
      #pragma unroll
      for (int i = 0; i < 4; i++){
        int rB = wn + i * 16 + fr;
        bb[i] = *(const s16x8*)(Bg_ + rB * 64 + (((kk*4 + quad) ^ (rB & 7)) * 8));
      }
      #pragma unroll
      for (int i = 0; i < 4; i++)
        #pragma unroll
        for (int j = 0; j < 4; j++)
          accg[i][j] = __builtin_amdgcn_mfma_f32_16x16x32_bf16(af[i], bb[j], accg[i][j], 0, 0, 0);
      #pragma unroll
      for (int i = 0; i < 4; i++){
        int rB = wn + i * 16 + fr;
        bb[i] = *(const s16x8*)(Bu_ + rB * 64 + (((kk*4 + quad) ^ (rB & 7)) * 8));
      }
      #pragma unroll
      for (int i = 0; i < 4; i++)
        #pragma unroll
        for (int j = 0; j < 4; j++)
          accu[i][j] = __builtin_amdgcn_mfma_f32_16x16x32_bf16(af[i], bb[j], accu[i][j], 0, 0, 0);
    }
  }
  #pragma unroll
  for (int i = 0; i < 4; i++){
    int row0 = m0 + wm + i * 16 + quad * 4;
    #pragma unroll
    for (int j = 0; j < 4; j++){
      int col = n0 + wn + j * 16 + fr;
      #pragma unroll
      for (int r = 0; r < 4; r++){
        float g = accg[i][j][r], u = accu[i][j][r];
        float act = g / (1.0f + __expf(-g)) * u;
        actb[(long)(row0 + r) * F_ + col] = f2bf(act);
      }
    }
  }
}

// ---------------------------------------------------------------------------
// Merged RoPE + V-transpose, reading bf16 qkvb laid out [m][3072]
// (cols 0..1023 q, 1024..2047 k, 2048..3071 v).
// Blocks [0, M_): rope for one (b,t). Blocks [M_, M_+1024): vtrans.
// ---------------------------------------------------------------------------
__global__ __launch_bounds__(256) void rope_vt_kernel(
    const u16* __restrict__ qkv, u16* __restrict__ qr, u16* __restrict__ kr,
    u16* __restrict__ vt)
{
  const int bid = blockIdx.x;
  if (bid < M_){
    const int m = bid;
    const int b = m >> 10, t = m & 1023;
    for (int w = threadIdx.x; w < 1024; w += 256){
      const int sel = w >> 9;          // 0=q 1=k
      const int hh  = (w >> 5) & 15;
      const int i   = w & 31;
      const u16* src = qkv + (long)m * 3072 + sel * 1024 + hh * HD_;
      float x1 = bf2f(src[i]), x2 = bf2f(src[i + 32]);
      float freq = exp2f((float)i * (-13.287712379549449f / 32.0f)); // 10000^(-i/32)
      float ang = (float)t * freq;
      float sn, cs; __sincosf(ang, &sn, &cs);
      u16* dst = (sel ? kr : qr) + ((long)((b * NH_ + hh) * T_ + t)) * HD_;
      dst[i]      = f2bf(x1 * cs - x2 * sn);
      dst[i + 32] = f2bf(x2 * cs + x1 * sn);
    }
  } else {
    const int v = bid - M_;            // 0..1023
    const int bh = v >> 5, tch = v & 31;
    const int b = bh >> 4, hh = bh & 15;
    const int d = threadIdx.x & 63, tc = threadIdx.x >> 6;
    const int t0 = tch * 32 + tc * 8;
    const u16* src = qkv + (long)(b * T_ + t0) * 3072 + 2048 + hh * HD_ + d;
    u16x8 o;
    #pragma unroll
    for (int j = 0; j < 8; j++) o[j] = src[(long)j * 3072];
    *(u16x8*)(vt + ((long)bh * HD_ + d) * T_ + t0) = o;
  }
}

// ---------------------------------------------------------------------------
// Flash attention, causal-balanced: grid (8, B_*NH_), 256 thr.
// Each block processes q-tiles qt and 15-qt (uniform 9 k-tile units/block).
// ---------------------------------------------------------------------------
__global__ __launch_bounds__(256, 2) void attn_kernel(
    const u16* __restrict__ qr, const u16* __restrict__ kr,
    const u16* __restrict__ vt, u16* __restrict__ att)
{
  const int bh = blockIdx.y;
  const int b = bh >> 4, hh = bh & 15;
  __shared__ alignas(16) u16 Qs[64 * 64];
  __shared__ alignas(16) u16 Ks[128 * 64];
  __shared__ alignas(16) u16 Vs[64 * 128];
  __shared__ alignas(16) u16 Ps[64 * 136];
  const int tid = threadIdx.x;
  const int wave = tid >> 6, lane = tid & 63, fr = lane & 15, quad = lane >> 4;
  const int wrow = wave * 16;
  const u16* kgb = kr + (long)bh * T_ * HD_;
  const u16* vgb = vt + (long)bh * HD_ * T_;

  for (int pass = 0; pass < 2; pass++){
    const int qt = pass ? (15 - (int)blockIdx.x) : (int)blockIdx.x;
    __syncthreads();   // guard Qs/Ks/Vs/Ps reuse across passes
    const u16* qg = qr + ((long)bh * T_ + qt * 64) * HD_;
    #pragma unroll
    for (int c = 0; c < 2; c++){
      int lin = c * 256 + tid, row = lin >> 3, p = lin & 7;
      async16(qg + row * HD_ + ((p ^ (row & 7)) * 8), Qs + lin * 8);
    }
    f32x4 o_acc[4] = {};
    float m_r[4] = {-1e30f, -1e30f, -1e30f, -1e30f};
    float l_r[4] = {};
    const int kmax = (qt * 64 + 63) >> 7;

    for (int kt = 0; kt <= kmax; kt++){
      __syncthreads();
      const u16* kg = kgb + (long)kt * 128 * HD_;
      #pragma unroll
      for (int c = 0; c < 4; c++){
        int lin = c * 256 + tid, row = lin >> 3, p = lin & 7;
        async16(kg + row * HD_ + ((p ^ (row & 7)) * 8), Ks + lin * 8);
      }
      #pragma unroll
      for (int c = 0; c < 4; c++){
        int lin = c * 256 + tid, row = lin >> 4, p = lin & 15;
        async16(vgb + (long)row * T_ + kt * 128 + ((p ^ (row & 15)) * 8), Vs + lin * 8);
      }
      __syncthreads();

      f32x4 s[8] = {};
      s16x8 aq[2];
      {
        int rA = wrow + fr;
        #pragma unroll
        for (int kk = 0; kk < 2; kk++)
          aq[kk] = *(const s16x8*)(Qs + rA * 64 + (((kk*4 + quad) ^ (rA & 7)) * 8));
      }
      #pragma unroll
      for (int ik = 0; ik < 8; ik++){
        #pragma unroll
        for (int kk = 0; kk < 2; kk++){
          int rB = ik * 16 + fr;
          s16x8 bk = *(const s16x8*)(Ks + rB * 64 + (((kk*4 + quad) ^ (rB & 7)) * 8));
          s[ik] = __builtin_amdgcn_mfma_f32_16x16x32_bf16(aq[kk], bk, s[ik], 0, 0, 0);
        }
      }
      const bool diag = (kt == kmax);
      #pragma unroll
      for (int r = 0; r < 4; r++){
        const int qgi = qt * 64 + wrow + quad * 4 + r;
        float tmax = -1e30f;
        #pragma unroll
        for (int ik = 0; ik < 8; ik++){
          float v = s[ik][r] * 0.125f;
          if (diag && (kt * 128 + ik * 16 + fr) > qgi) v = -1e9f;
          s[ik][r] = v;
          tmax = fmaxf(tmax, v);
        }
        #pragma unroll
        for (int off = 8; off >= 1; off >>= 1) tmax = fmaxf(tmax, __shfl_xor(tmax, off));
        const float mnew = fmaxf(m_r[r], tmax);
        const float alpha = __expf(m_r[r] - mnew);
        m_r[r] = mnew;
        float ts = 0.0f;
        const int prow = wrow + quad * 4 + r;
        #pragma unroll
        for (int ik = 0; ik < 8; ik++){
          float p = __expf(s[ik][r] - mnew);
          ts += p;
          Ps[prow * 136 + ik * 16 + fr] = f2bf(p);
        }
        #pragma unroll
        for (int off = 8; off >= 1; off >>= 1) ts += __shfl_xor(ts, off);
        l_r[r] = l_r[r] * alpha + ts;
        #pragma unroll
        for (int jd = 0; jd < 4; jd++) o_acc[jd][r] *= alpha;
      }
      #pragma unroll
      for (int kk2 = 0; kk2 < 4; kk2++){
        s16x8 ap = *(const s16x8*)(Ps + (wrow + fr) * 136 + kk2 * 32 + quad * 8);
        #pragma unroll
        for (int jd = 0; jd < 4; jd++){
          int rV = jd * 16 + fr;
          s16x8 bv = *(const s16x8*)(Vs + rV * 128 + (((kk2*4 + quad) ^ (rV & 15)) * 8));
          o_acc[jd] = __builtin_amdgcn_mfma_f32_16x16x32_bf16(ap, bv, o_acc[jd], 0, 0, 0);
        }
      }
    }
    #pragma unroll
    for (int r = 0; r < 4; r++){
      const int t_loc = qt * 64 + wrow + quad * 4 + r;
      const long rowbase = ((long)b * T_ + t_loc) * H_ + hh * HD_;
      const float inv = 1.0f / l_r[r];
      #pragma unroll
      for (int jd = 0; jd < 4; jd++)
        att[rowbase + jd * 16 + fr] = f2bf(o_acc[jd][r] * inv);
    }
  }
}

// ---------------------------------------------------------------------------
// Final: h' = h + p0 + p1; rms(h',ln_f) @ head_W + b, clamp, softmax/T.
// grid M_, 256 thr. out = [weights (M_*31), logits (M_*31)]
// ---------------------------------------------------------------------------
__global__ __launch_bounds__(256) void head_kernel(
    const float* __restrict__ hsrc, const float* __restrict__ p0, const float* __restrict__ p1,
    const float* __restrict__ lnf, const float* __restrict__ hw, const float* __restrict__ hb,
    const float* __restrict__ temp, float* __restrict__ outp)
{
  const int m = blockIdx.x, t = threadIdx.x;
  __shared__ float lat[H_];
  __shared__ float red[4];
  __shared__ float part[8][32];
  float4 v = ((const float4*)(hsrc + (long)m * H_))[t];
  {
    const float4 a = ((const float4*)(p0 + (long)m * H_))[t];
    const float4 b = ((const float4*)(p1 + (long)m * H_))[t];
    v.x += a.x + b.x; v.y += a.y + b.y; v.z += a.z + b.z; v.w += a.w + b.w;
  }
  float ss = v.x*v.x + v.y*v.y + v.z*v.z + v.w*v.w;
  #pragma unroll
  for (int off = 32; off >= 1; off >>= 1) ss += __shfl_xor(ss, off);
  if ((t & 63) == 0) red[t >> 6] = ss;
  __syncthreads();
  const float scale = rsqrtf((red[0]+red[1]+red[2]+red[3]) * (1.0f/H_) + 1e-6f);
  const float4 wv = ((const float4*)lnf)[t];
  lat[t*4+0] = v.x*scale*wv.x;  lat[t*4+1] = v.y*scale*wv.y;
  lat[t*4+2] = v.z*scale*wv.z;  lat[t*4+3] = v.w*scale*wv.w;
  __syncthreads();
  const int j = t & 31, seg = t >> 5;
  float pp = 0.0f;
  if (j < 31){
    const float* wp = hw + j;
    for (int k = seg * 128; k < seg * 128 + 128; k++) pp += lat[k] * wp[(long)k * 31];
  }
  part[seg][j] = pp;
  __syncthreads();
  if (t < 32){
    float dot = 0.0f;
    #pragma unroll
    for (int s2 = 0; s2 < 8; s2++) dot += part[s2][t];
    const float logit = (t < 31) ? dot + hb[t] : -1e30f;
    const float lc = fminf(fmaxf(logit, -10.0f), 10.0f);
    const float z = (t < 31) ? lc / temp[0] : -1e30f;
    float mx = z;
    #pragma unroll
    for (int off = 16; off >= 1; off >>= 1) mx = fmaxf(mx, __shfl_xor(mx, off, 32));
    const float e = (t < 31) ? __expf(z - mx) : 0.0f;
    float sum = e;
    #pragma unroll
    for (int off = 16; off >= 1; off >>= 1) sum += __shfl_xor(sum, off, 32);
    if (t < 31){
      outp[(long)m * NTP1_ + t] = e / sum;
      outp[(long)M_ * NTP1_ + (long)m * NTP1_ + t] = lc;
    }
  }
}

// ---------------------------------------------------------------------------
extern "C" void kernel_launch(void* const* d_in, const int* in_sizes, int n_in,
                              void* d_out, int out_size, void* d_ws, size_t ws_size,
                              hipStream_t stream) {
  const float* x    = (const float*)d_in[0];
  const float* temp = (const float*)d_in[1];
  const float* sW   = (const float*)d_in[2];
  const float* sb   = (const float*)d_in[3];
  const float* ln1  = (const float*)d_in[4];
  const float* ln2  = (const float*)d_in[5];
  const float* Wqkv = (const float*)d_in[6];
  const float* Aqkv = (const float*)d_in[7];
  const float* Bqkv = (const float*)d_in[8];
  const float* Wo   = (const float*)d_in[9];
  const float* Ao   = (const float*)d_in[10];
  const float* Bo   = (const float*)d_in[11];
  const float* Wgu  = (const float*)d_in[12];
  const float* Agu  = (const float*)d_in[13];
  const float* Bgu  = (const float*)d_in[14];
  const float* Wd   = (const float*)d_in[15];
  const float* Ad   = (const float*)d_in[16];
  const float* Bd   = (const float*)d_in[17];
  const float* lnf  = (const float*)d_in[18];
  const float* hW   = (const float*)d_in[19];
  const float* hb   = (const float*)d_in[20];
  float* out = (float*)d_out;

  uint8_t* ws = (uint8_t*)d_ws;
  size_t off = 0;
  auto alloc = [&](size_t bytes) -> void* {
    void* p = ws + off;
    off += (bytes + 255) & ~(size_t)255;
    return p;
  };
  u16*   wt_qkv = (u16*)  alloc((size_t)L_ * 3 * H_ * H_ * 2);
  u16*   wt_o   = (u16*)  alloc((size_t)L_ * H_ * H_ * 2);
  u16*   wt_gu  = (u16*)  alloc((size_t)L_ * 2 * F_ * H_ * 2);
  u16*   wt_d   = (u16*)  alloc((size_t)L_ * H_ * F_ * 2);
  float* h      = (float*)alloc((size_t)M_ * H_ * 4);
  u16*   hn     = (u16*)  alloc((size_t)M_ * H_ * 2);
  u16*   qkvb   = (u16*)  alloc((size_t)M_ * 3072 * 2);     // [m][3072] bf16
  float* p0     = (float*)alloc((size_t)2 * M_ * H_ * 4);   // o/d split-K partials
  float* p1     = p0 + (size_t)M_ * H_;
  u16*   qr     = (u16*)  alloc((size_t)M_ * H_ * 2);
  u16*   krr    = (u16*)  alloc((size_t)M_ * H_ * 2);
  u16*   vtb    = (u16*)  alloc((size_t)M_ * H_ * 2);
  u16*   attb   = (u16*)  alloc((size_t)M_ * H_ * 2);
  u16*   actb   = (u16*)  alloc((size_t)M_ * F_ * 2);

  // --- per-launch weight fold+convert+transpose ---
  fold_kernel<<<dim3(16, 16, L_ * 3), 256, 0, stream>>>(Wqkv, Aqkv, Bqkv, wt_qkv,
      H_, H_, (long)H_ * H_, (long)R_ * H_, (long)H_ * R_, (long)H_ * H_);
  fold_kernel<<<dim3(16, 16, L_), 256, 0, stream>>>(Wo, Ao, Bo, wt_o,
      H_, H_, (long)H_ * H_, (long)R_ * H_, (long)H_ * R_, (long)H_ * H_);
  fold_kernel<<<dim3(16, 44, L_ * 2), 256, 0, stream>>>(Wgu, Agu, Bgu, wt_gu,
      H_, F_, (long)H_ * F_, (long)R_ * H_, (long)F_ * R_, (long)F_ * H_);
  fold_kernel<<<dim3(44, 16, L_), 256, 0, stream>>>(Wd, Ad, Bd, wt_d,
      F_, H_, (long)F_ * H_, (long)R_ * F_, (long)H_ * R_, (long)H_ * F_);

  embed_kernel<<<M_, 256, 0, stream>>>(x, sW, sb, h);

  for (int l = 0; l < L_; l++){
    // h += d-partials of previous layer (l>0), then rms -> hn
    rms_kernel<<<M_, 256, 0, stream>>>(h, p0, p1, ln1 + (long)l * H_, hn, l > 0 ? 1 : 0);
    // qkv: single GEMM, N=3072 (3 mats contiguous n-major), bf16 out [m][3072]
    gemm_bt<1><<<dim3(16, 24, 1), 256, 0, stream>>>(hn, wt_qkv + (long)l * 3 * H_ * H_,
        qkvb, 3072, 1024, 1024, 0, 0, 0);
    rope_vt_kernel<<<M_ + 1024, 256, 0, stream>>>(qkvb, qr, krr, vtb);
    attn_kernel<<<dim3(8, B_ * NH_), 256, 0, stream>>>(qr, krr, vtb, attb);
    // o-proj: split-K=2 partials into p0/p1
    gemm_bt<0><<<dim3(16, 8, 2), 256, 0, stream>>>(attb, wt_o + (long)l * H_ * H_,
        p0, H_, 512, H_, 512, 512, (long)M_ * H_);
    // h += o-partials, rms -> hn
    rms_kernel<<<M_, 256, 0, stream>>>(h, p0, p1, ln2 + (long)l * H_, hn, 1);
    // fused gate/up GEMM + silu -> actb (bf16)
    gemm_gu<<<dim3(16, 22), 256, 0, stream>>>(hn,
        wt_gu + (long)l * 2 * F_ * H_, wt_gu + (long)l * 2 * F_ * H_ + (long)F_ * H_, actb);
    // down-proj: split-K=2 partials into p0/p1
    gemm_bt<0><<<dim3(16, 8, 2), 256, 0, stream>>>(actb, wt_d + (long)l * H_ * F_,
        p0, H_, 1408, F_, 1408, 1408, (long)M_ * H_);
  }

  head_kernel<<<M_, 256, 0, stream>>>(h, p0, p1, lnf, hW, hb, temp, out);
}